// Round 5
// baseline (143.558 us; speedup 1.0000x reference)
//
#include <hip/hip_runtime.h>
#include <hip/hip_bf16.h>

#define DIN 64
#define DOUT 62
#define ICH 32
#define OCH 64

typedef __bf16 bf16x8 __attribute__((ext_vector_type(8)));
typedef float f32x4 __attribute__((ext_vector_type(4)));
typedef float f32x8 __attribute__((ext_vector_type(8)));

// ---------- prep: W[oc][ic][kz][ky][kx] f32 -> Wre[tap][oc][ic] bf16(ushort) ----------
__global__ void prep_w(const float* __restrict__ W, unsigned short* __restrict__ Wre) {
    int idx = blockIdx.x * 256 + threadIdx.x;        // 27*64*32 = 55296
    if (idx >= 27 * OCH * ICH) return;
    int ic  = idx & 31;
    int oc  = (idx >> 5) & 63;
    int tap = idx >> 11;
    float v = W[((size_t)oc * ICH + ic) * 27 + tap];
    Wre[idx] = __builtin_bit_cast(unsigned short, (__bf16)v);
}

// ---------- main: implicit GEMM, kz-outer, rolling 2-plane LDS dbuf (50.7 KB) ----------
// block tile: (b, d, 4 h-rows) x 64 oc x 64 w.  wave = one h row.
// LDS plane: [y(6)][w(66)][4 slots of 16B(8 ic bf16)], slot = icg ^ ((w>>1)&3)
// Staging rows ride in f32x8 SSA values (3-deep rotate) -> no scratch spill.
template<bool USE_WRE>
__global__ __launch_bounds__(256, 3) void conv3d_mfma(
    const float* __restrict__ x, const float* __restrict__ W,
    const unsigned short* __restrict__ Wre, float* __restrict__ out)
{
    __shared__ char xs[2][6 * 66 * 64];              // 2 x 25,344 B

    const int tid  = threadIdx.x;
    const int lane = tid & 63;
    const int wave = tid >> 6;

    // bijective XCD-aware swizzle (nwg = 1984 = 8*248 exactly)
    const int orig = blockIdx.x;
    const int lid  = (orig & 7) * 248 + (orig >> 3);
    const int ht = lid & 15;
    const int rr = lid >> 4;
    const int d  = rr % DOUT;
    const int b  = rr / DOUT;
    const int h0 = ht * 4;

    const int wlo = lane & 15;                       // w-in-tile / oc-in-tile
    const int whi = lane >> 4;                       // k-group (8 ic)
    const int row = wave;                            // h row

    // staging role: thread (wave=icg, lane=w)
    const int icg  = wave;
    const int w    = lane;
    const int slot = icg ^ ((w >> 1) & 3);

    auto issueRow = [&](int z, int y) -> f32x8 {     // 8 ic-strided f32 loads
        int gy = h0 + y; if (gy > 63) gy = 63;       // clamped rows feed only discarded h
        const float* xp = x + (((size_t)(b * ICH + icg * 8) * DIN + z) * DIN + gy) * DIN + w;
        f32x8 s;
#pragma unroll
        for (int j = 0; j < 8; ++j) s[j] = xp[(size_t)j * DIN * DIN * DIN];
        return s;
    };
    auto writeRow = [&](char* buf, int y, f32x8 s) { // cvt + one ds_write_b128
        bf16x8 pk;
#pragma unroll
        for (int j = 0; j < 8; ++j) pk[j] = (__bf16)s[j];
        *(int4*)(buf + ((y * 66 + w) * 64 + slot * 16)) = __builtin_bit_cast(int4, pk);
    };
    auto loadA = [&](int tap, int4* af) {
        if (USE_WRE) {
            const char* wp = (const char*)Wre + (size_t)tap * (OCH * ICH * 2) + whi * 16;
#pragma unroll
            for (int mt = 0; mt < 4; ++mt)
                af[mt] = *(const int4*)(wp + (mt * 16 + wlo) * 64);
        } else {
#pragma unroll
            for (int mt = 0; mt < 4; ++mt) {
                const float* wp = W + ((size_t)(mt * 16 + wlo) * ICH + whi * 8) * 27 + tap;
                bf16x8 t;
#pragma unroll
                for (int j = 0; j < 8; ++j) t[j] = (__bf16)wp[j * 27];
                af[mt] = __builtin_bit_cast(int4, t);
            }
        }
    };

    // zero the w=64,65 pad columns of BOTH buffers once (never overwritten later)
    if (tid < 96) {
        int bu = tid / 48, q2 = tid % 48;
        int y = q2 >> 3, q = q2 & 7;
        int w2 = 64 + (q >> 2), sl = q & 3;
        *(int4*)(xs[bu] + ((y * 66 + w2) * 64 + sl * 16)) = int4{0, 0, 0, 0};
    }

    // prologue: stage plane d into buf0, <=3 rows in flight
    {
        f32x8 s0 = issueRow(d, 0), s1 = issueRow(d, 1), s2 = issueRow(d, 2);
        writeRow(xs[0], 0, s0); s0 = issueRow(d, 3);
        writeRow(xs[0], 1, s1); s1 = issueRow(d, 4);
        writeRow(xs[0], 2, s2); s2 = issueRow(d, 5);
        writeRow(xs[0], 3, s0); writeRow(xs[0], 4, s1); writeRow(xs[0], 5, s2);
    }
    int4 af[2][4];
    loadA(0, af[0]);
    __syncthreads();

    f32x4 acc[4][4];
#pragma unroll
    for (int mt = 0; mt < 4; ++mt)
#pragma unroll
        for (int nt = 0; nt < 4; ++nt)
            acc[mt][nt] = f32x4{0.f, 0.f, 0.f, 0.f};

#pragma unroll                                        // kz compile-time -> all indices static
    for (int kz = 0; kz < 3; ++kz) {
        char* cur = xs[kz & 1];
        char* nxt = xs[(kz + 1) & 1];
        f32x8 s0, s1, s2;                            // rotate-by-3, all picks compile-time

#pragma unroll
        for (int t = 0; t < 9; ++t) {
            const int T  = kz * 9 + t;
            const int ky = t / 3, kx = t % 3;

            // B fragments from LDS first (critical path to MFMA)
            bf16x8 bfr[4];
#pragma unroll
            for (int nt = 0; nt < 4; ++nt) {
                int wb = nt * 16 + wlo + kx;
                int sl = whi ^ ((wb >> 1) & 3);
                bfr[nt] = __builtin_bit_cast(bf16x8,
                    *(const int4*)(cur + (((row + ky) * 66 + wb) * 64 + sl * 16)));
            }

            if (T < 26) loadA(T + 1, af[(T + 1) & 1]);   // 1-deep A prefetch

            // rolling stage of next plane: write row t-3, then issue row t
            if (kz < 2) {
                if (t == 3) writeRow(nxt, 0, s0);
                if (t == 4) writeRow(nxt, 1, s1);
                if (t == 5) writeRow(nxt, 2, s2);
                if (t == 6) writeRow(nxt, 3, s0);
                if (t == 7) writeRow(nxt, 4, s1);
                if (t == 8) writeRow(nxt, 5, s2);
                if (t == 0) s0 = issueRow(d + kz + 1, 0);
                if (t == 1) s1 = issueRow(d + kz + 1, 1);
                if (t == 2) s2 = issueRow(d + kz + 1, 2);
                if (t == 3) s0 = issueRow(d + kz + 1, 3);
                if (t == 4) s1 = issueRow(d + kz + 1, 4);
                if (t == 5) s2 = issueRow(d + kz + 1, 5);
            }

#pragma unroll
            for (int mt = 0; mt < 4; ++mt)
#pragma unroll
                for (int nt = 0; nt < 4; ++nt)
                    acc[mt][nt] = __builtin_amdgcn_mfma_f32_16x16x32_bf16(
                        __builtin_bit_cast(bf16x8, af[T & 1][mt]), bfr[nt], acc[mt][nt], 0, 0, 0);
        }
        if (kz < 2) __syncthreads();                  // next plane ready; one barrier/segment
    }

    // ---- store: D row=(l>>4)*4+r -> oc, col=l&15 -> w  (nontemporal: out never re-read) ----
    const int h = h0 + row;
    if (h < DOUT) {
#pragma unroll
        for (int mt = 0; mt < 4; ++mt) {
#pragma unroll
            for (int r = 0; r < 4; ++r) {
                int oc = mt * 16 + whi * 4 + r;
                size_t ob = ((((size_t)b * OCH + oc) * DOUT + d) * DOUT + h) * DOUT;
#pragma unroll
                for (int nt = 0; nt < 4; ++nt) {
                    int ww = nt * 16 + wlo;
                    if (ww < DOUT)
                        __builtin_nontemporal_store(acc[mt][nt][r], &out[ob + ww]);
                }
            }
        }
    }
}

extern "C" void kernel_launch(void* const* d_in, const int* in_sizes, int n_in,
                              void* d_out, int out_size, void* d_ws, size_t ws_size,
                              hipStream_t stream) {
    const float* x = (const float*)d_in[0];
    const float* W = (const float*)d_in[1];
    float* out = (float*)d_out;

    const dim3 grid(2 * DOUT * 16);                  // 1984 blocks = 8 XCDs * 248
    const size_t wre_bytes = (size_t)27 * OCH * ICH * 2;

    if (ws_size >= wre_bytes) {
        unsigned short* Wre = (unsigned short*)d_ws;
        prep_w<<<dim3((27 * OCH * ICH + 255) / 256), 256, 0, stream>>>(W, Wre);
        conv3d_mfma<true><<<grid, 256, 0, stream>>>(x, W, Wre, out);
    } else {
        conv3d_mfma<false><<<grid, 256, 0, stream>>>(x, W, nullptr, out);
    }
}

// Round 6
// 138.435 us; speedup vs baseline: 1.0370x; 1.0370x over previous
//
#include <hip/hip_runtime.h>
#include <hip/hip_bf16.h>

#define DIN 64
#define DOUT 62
#define ICH 32
#define OCH 64

typedef __bf16 bf16x8 __attribute__((ext_vector_type(8)));
typedef float f32x4 __attribute__((ext_vector_type(4)));
typedef float f32x8 __attribute__((ext_vector_type(8)));

// ---------- prep: W[oc][ic][kz][ky][kx] f32 -> Wre[tap][oc][ic] bf16(ushort) ----------
__global__ void prep_w(const float* __restrict__ W, unsigned short* __restrict__ Wre) {
    int idx = blockIdx.x * 256 + threadIdx.x;        // 27*64*32 = 55296
    if (idx >= 27 * OCH * ICH) return;
    int ic  = idx & 31;
    int oc  = (idx >> 5) & 63;
    int tap = idx >> 11;
    float v = W[((size_t)oc * ICH + ic) * 27 + tap];
    Wre[idx] = __builtin_bit_cast(unsigned short, (__bf16)v);
}

// ---------- main: implicit GEMM, kz-outer, rolling 2-plane LDS dbuf ----------
// block tile: (b, d, 4 h-rows) x 64 oc x 64 w.  wave = one h row.
// LDS plane: [y(6)][w(66)][4 slots of 16B(8 ic bf16)], slot = icg ^ ((w>>1)&3)
// A (W) prefetched 1 tap ahead from L2; B (x) double-buffered 1 tap ahead from LDS.
template<bool USE_WRE>
__global__ __launch_bounds__(256, 3) void conv3d_mfma(
    const float* __restrict__ x, const float* __restrict__ W,
    const unsigned short* __restrict__ Wre, float* __restrict__ out)
{
    __shared__ char xs[2][6 * 66 * 64];              // 2 x 25,344 B

    const int tid  = threadIdx.x;
    const int lane = tid & 63;
    const int wave = tid >> 6;

    // bijective XCD-aware swizzle (nwg = 1984 = 8*248 exactly)
    const int orig = blockIdx.x;
    const int lid  = (orig & 7) * 248 + (orig >> 3);
    const int ht = lid & 15;
    const int rr = lid >> 4;
    const int d  = rr % DOUT;
    const int b  = rr / DOUT;
    const int h0 = ht * 4;

    const int wlo = lane & 15;                       // w-in-tile / oc-in-tile
    const int whi = lane >> 4;                       // k-group (8 ic)
    const int row = wave;                            // h row

    // staging role: thread (wave=icg, lane=w)
    const int icg  = wave;
    const int w    = lane;
    const int slot = icg ^ ((w >> 1) & 3);

    auto issueRow = [&](int z, int y) -> f32x8 {     // 8 ic-strided f32 loads (each wave-coalesced)
        int gy = h0 + y; if (gy > 63) gy = 63;       // clamped rows feed only discarded h
        const float* xp = x + (((size_t)(b * ICH + icg * 8) * DIN + z) * DIN + gy) * DIN + w;
        f32x8 s;
#pragma unroll
        for (int j = 0; j < 8; ++j) s[j] = xp[(size_t)j * DIN * DIN * DIN];
        return s;
    };
    auto writeRow = [&](char* buf, int y, f32x8 s) { // cvt + one ds_write_b128
        bf16x8 pk;
#pragma unroll
        for (int j = 0; j < 8; ++j) pk[j] = (__bf16)s[j];
        *(int4*)(buf + ((y * 66 + w) * 64 + slot * 16)) = __builtin_bit_cast(int4, pk);
    };
    auto loadA = [&](int tap, int4* af) {
        if (USE_WRE) {
            const char* wp = (const char*)Wre + (size_t)tap * (OCH * ICH * 2) + whi * 16;
#pragma unroll
            for (int mt = 0; mt < 4; ++mt)
                af[mt] = *(const int4*)(wp + (mt * 16 + wlo) * 64);
        } else {
#pragma unroll
            for (int mt = 0; mt < 4; ++mt) {
                const float* wp = W + ((size_t)(mt * 16 + wlo) * ICH + whi * 8) * 27 + tap;
                bf16x8 t;
#pragma unroll
                for (int j = 0; j < 8; ++j) t[j] = (__bf16)wp[j * 27];
                af[mt] = __builtin_bit_cast(int4, t);
            }
        }
    };
    auto readB = [&](const char* buf, int ky, int kx, int4* dst) {   // 4 ds_read_b128
#pragma unroll
        for (int nt = 0; nt < 4; ++nt) {
            int wb = nt * 16 + wlo + kx;
            int sl = whi ^ ((wb >> 1) & 3);
            dst[nt] = *(const int4*)(buf + (((row + ky) * 66 + wb) * 64 + sl * 16));
        }
    };

    // zero the w=64,65 pad columns of BOTH buffers once (never overwritten later)
    if (tid < 96) {
        int bu = tid / 48, q2 = tid % 48;
        int y = q2 >> 3, q = q2 & 7;
        int w2 = 64 + (q >> 2), sl = q & 3;
        *(int4*)(xs[bu] + ((y * 66 + w2) * 64 + sl * 16)) = int4{0, 0, 0, 0};
    }

    // prologue: stage plane d into buf0, <=3 rows in flight
    {
        f32x8 s0 = issueRow(d, 0), s1 = issueRow(d, 1), s2 = issueRow(d, 2);
        writeRow(xs[0], 0, s0); s0 = issueRow(d, 3);
        writeRow(xs[0], 1, s1); s1 = issueRow(d, 4);
        writeRow(xs[0], 2, s2); s2 = issueRow(d, 5);
        writeRow(xs[0], 3, s0); writeRow(xs[0], 4, s1); writeRow(xs[0], 5, s2);
    }
    int4 af[2][4];
    loadA(0, af[0]);
    __syncthreads();

    f32x4 acc[4][4];
#pragma unroll
    for (int mt = 0; mt < 4; ++mt)
#pragma unroll
        for (int nt = 0; nt < 4; ++nt)
            acc[mt][nt] = f32x4{0.f, 0.f, 0.f, 0.f};

    int4 bfr[2][4];

#pragma unroll                                        // kz compile-time -> all indices static
    for (int kz = 0; kz < 3; ++kz) {
        char* cur = xs[kz & 1];
        char* nxt = xs[(kz + 1) & 1];
        f32x8 s0, s1, s2;                            // rotate-by-3, all picks compile-time

        readB(cur, 0, 0, bfr[0]);                    // per-kz B prologue (one exposed LDS latency)

#pragma unroll
        for (int t = 0; t < 9; ++t) {
            const int T = kz * 9 + t;

            if (T < 26) loadA(T + 1, af[(T + 1) & 1]);       // 1-deep A prefetch (L2)
            if (t < 8)  readB(cur, (t + 1) / 3, (t + 1) % 3, bfr[(t + 1) & 1]);  // 1-deep B prefetch (LDS)

            // rolling stage of next plane: write row t-3, then issue row t
            if (kz < 2) {
                if (t == 3) writeRow(nxt, 0, s0);
                if (t == 4) writeRow(nxt, 1, s1);
                if (t == 5) writeRow(nxt, 2, s2);
                if (t == 6) writeRow(nxt, 3, s0);
                if (t == 7) writeRow(nxt, 4, s1);
                if (t == 8) writeRow(nxt, 5, s2);
                if (t == 0) s0 = issueRow(d + kz + 1, 0);
                if (t == 1) s1 = issueRow(d + kz + 1, 1);
                if (t == 2) s2 = issueRow(d + kz + 1, 2);
                if (t == 3) s0 = issueRow(d + kz + 1, 3);
                if (t == 4) s1 = issueRow(d + kz + 1, 4);
                if (t == 5) s2 = issueRow(d + kz + 1, 5);
            }

#pragma unroll
            for (int mt = 0; mt < 4; ++mt)
#pragma unroll
                for (int nt = 0; nt < 4; ++nt)
                    acc[mt][nt] = __builtin_amdgcn_mfma_f32_16x16x32_bf16(
                        __builtin_bit_cast(bf16x8, af[T & 1][mt]),
                        __builtin_bit_cast(bf16x8, bfr[t & 1][nt]),
                        acc[mt][nt], 0, 0, 0);
        }
        if (kz < 2) __syncthreads();                  // next plane ready; one barrier/segment
    }

    // ---- store: D row=(l>>4)*4+r -> oc, col=l&15 -> w  (nontemporal: out never re-read) ----
    const int h = h0 + row;
    if (h < DOUT) {
#pragma unroll
        for (int mt = 0; mt < 4; ++mt) {
#pragma unroll
            for (int r = 0; r < 4; ++r) {
                int oc = mt * 16 + whi * 4 + r;
                size_t ob = ((((size_t)b * OCH + oc) * DOUT + d) * DOUT + h) * DOUT;
#pragma unroll
                for (int nt = 0; nt < 4; ++nt) {
                    int ww = nt * 16 + wlo;
                    if (ww < DOUT)
                        __builtin_nontemporal_store(acc[mt][nt][r], &out[ob + ww]);
                }
            }
        }
    }
}

extern "C" void kernel_launch(void* const* d_in, const int* in_sizes, int n_in,
                              void* d_out, int out_size, void* d_ws, size_t ws_size,
                              hipStream_t stream) {
    const float* x = (const float*)d_in[0];
    const float* W = (const float*)d_in[1];
    float* out = (float*)d_out;

    const dim3 grid(2 * DOUT * 16);                  // 1984 blocks = 8 XCDs * 248
    const size_t wre_bytes = (size_t)27 * OCH * ICH * 2;

    if (ws_size >= wre_bytes) {
        unsigned short* Wre = (unsigned short*)d_ws;
        prep_w<<<dim3((27 * OCH * ICH + 255) / 256), 256, 0, stream>>>(W, Wre);
        conv3d_mfma<true><<<grid, 256, 0, stream>>>(x, W, Wre, out);
    } else {
        conv3d_mfma<false><<<grid, 256, 0, stream>>>(x, W, nullptr, out);
    }
}